// Round 10
// baseline (74.698 us; speedup 1.0000x reference)
//
#include <hip/hip_runtime.h>
#include <hip/hip_bf16.h>
#include <math.h>

#define M 4096
#define ALPHA 0.2f
#define L2E 1.4426950408889634f

typedef __attribute__((ext_vector_type(8))) short bf16x8_t;   // 8 bf16 = 4 VGPRs
typedef __attribute__((ext_vector_type(4))) float f32x4_t;    // MFMA accumulator

#define EXP2F(x) __builtin_amdgcn_exp2f(x)   // v_exp_f32: 2^x

// round-to-nearest-even float -> bf16 bits (cold paths)
__device__ inline unsigned short f2bf(float f) {
    unsigned int u = __float_as_uint(f);
    u = (u + 0x7fffu + ((u >> 16) & 1u)) >> 16;
    return (unsigned short)u;
}
// round-half-up float -> bf16 bits (hot path; p >= 0 finite)
__device__ inline unsigned short f2bf_fast(float f) {
    return (unsigned short)((__float_as_uint(f) + 0x8000u) >> 16);
}

// WhB fragment-layout index: [k-word][fblk][lane(=kg*16+fl)][j]
__device__ inline size_t whb_idx(int i, int c, int NFB) {
    return (((size_t)(i >> 5) * NFB + (c >> 4)) * 64 +
            (((i & 31) >> 3) * 16 + (c & 15))) * 8 + (i & 7);
}

// ---------------- K1 (fat): pack adj -> packedT  ||  Wh1 = h0@W1 + WhB1 + s_i/s_k ----------
#define PACK_BLOCKS (M * M / 4 / 256)      // 16384
template <int DIN, int F>
__global__ __launch_bounds__(256) void prep_fat_kernel(const int* __restrict__ adj,
                                                       unsigned int* __restrict__ packedT,
                                                       const float* __restrict__ h0,
                                                       const float* __restrict__ W,
                                                       const float* __restrict__ a,
                                                       unsigned short* __restrict__ WhB,
                                                       float* __restrict__ s_i,
                                                       float* __restrict__ s_k) {
    int lane = threadIdx.x & 63;
    if (blockIdx.x < PACK_BLOCKS) {
        // ---- pack: one int4 per thread, 8-lane shfl merge ----
        int g = blockIdx.x * 256 + threadIdx.x;        // int4 index over M*M/4
        int4 av = ((const int4*)adj)[g];
        unsigned int nib = (av.x > 0 ? 1u : 0u) | (av.y > 0 ? 2u : 0u) |
                           (av.z > 0 ? 4u : 0u) | (av.w > 0 ? 8u : 0u);
        unsigned int sh = nib << ((lane & 7) * 4);
        sh |= __shfl_xor(sh, 1);
        sh |= __shfl_xor(sh, 2);
        sh |= __shfl_xor(sh, 4);
        if ((lane & 7) == 0) {
            int kw = (g >> 3) & 127;
            int i  = g >> 10;
            packedT[(size_t)kw * M + i] = sh;
        }
        return;
    }
    // ---- fused_in: one wave per row ----
    int wave = threadIdx.x >> 6;
    int i = (blockIdx.x - PACK_BLOCKS) * 4 + wave;
    float acc = 0.f;                                   // Wh[i][lane]
#pragma unroll
    for (int j = 0; j < DIN; j++)
        acc += h0[(size_t)i * DIN + j] * W[j * F + lane];
    float vi = acc * a[lane], vk = acc * a[F + lane];
#pragma unroll
    for (int off = 32; off; off >>= 1) { vi += __shfl_xor(vi, off); vk += __shfl_xor(vk, off); }
    if (lane == 0) { s_i[i] = vi; s_k[i] = vk; }
    WhB[whb_idx(i, lane, F / 16)] = f2bf(acc);
}

// ---------------- full-K MFMA attention, in-block wave split-K + fused epilogue ----------
// Block = 16 rows, 4 waves each owning a K-quarter (1024). acc reduced in LDS.
// FINAL=false (layer1, F=64): epilogue = normalize+ELU -> h1 -> Wh2=h1@W2 -> WhB2/si2/sk2.
// FINAL=true  (layer2, F=32): epilogue = normalize+ELU -> hL write + omega dots -> pi/pk.
template <int F, bool FINAL>
__global__ __launch_bounds__(256) void attn_full_kernel(const unsigned short* __restrict__ WhB,
                                                        const float* __restrict__ s_i,
                                                        const float* __restrict__ s_k,
                                                        const unsigned int* __restrict__ packedT,
                                                        const float* __restrict__ W2,
                                                        const float* __restrict__ a2,
                                                        unsigned short* __restrict__ WhB2,
                                                        float* __restrict__ si2,
                                                        float* __restrict__ sk2,
                                                        const float* __restrict__ omega,
                                                        float* __restrict__ hL_out,
                                                        float* __restrict__ p_i,
                                                        float* __restrict__ p_k) {
    constexpr int NFB = F / 16;
    constexpr int KW = M / 32;                         // 128 mask words per row
    __shared__ unsigned int mask_lds[16][KW + 1];      // 8.3 KB
    __shared__ float acc_lds[4][16][F + 1];            // 16.6 / 8.4 KB
    __shared__ float sred[4][16];
    __shared__ float wred[4];
    __shared__ float h_lds[16][F];

    int tid = threadIdx.x, wave = tid >> 6, lane = tid & 63;
    int R0 = blockIdx.x * 16;

    // in-block global skmax (deterministic, identical across blocks)
    float m = -INFINITY;
    for (int j = tid; j < M; j += 256) m = fmaxf(m, s_k[j]);
#pragma unroll
    for (int off = 32; off; off >>= 1) m = fmaxf(m, __shfl_xor(m, off));
    if (lane == 0) wred[wave] = m;

    // stage mask tile: 16 rows x 128 words
#pragma unroll
    for (int q = 0; q < 8; q++) {
        int lin = q * 256 + tid;
        int kw = lin >> 4, r = lin & 15;
        mask_lds[r][kw] = packedT[(size_t)kw * M + R0 + r];
    }
    __syncthreads();
    float skmax = fmaxf(fmaxf(wred[0], wred[1]), fmaxf(wred[2], wred[3]));

    int fl = lane & 15, kg = lane >> 4;
    int row = R0 + fl;
    float si = s_i[row];
    float xm = si + skmax;
    float rl2 = fmaxf(xm, ALPHA * xm) * L2E;
    f32x4_t acc[NFB];
#pragma unroll
    for (int fb = 0; fb < NFB; fb++) acc[fb] = (f32x4_t)0.f;
    float rsum = 0.f;
    const int kw0 = wave * (KW / 4);                   // 32 words per wave
    for (int st = 0; st < KW / 4; st++) {
        int kb = (kw0 + st) * 32;
        float4 sa = *(const float4*)&s_k[kb + kg * 8];
        float4 sb = *(const float4*)&s_k[kb + kg * 8 + 4];
        unsigned int word = mask_lds[fl][kw0 + st];
        float sv[8] = { sa.x, sa.y, sa.z, sa.w, sb.x, sb.y, sb.z, sb.w };
        union { bf16x8_t v; unsigned short u[8]; } af;
#pragma unroll
        for (int j = 0; j < 8; j++) {
            float x = si + sv[j];
            float e = fmaxf(x, ALPHA * x);             // leakyrelu
            float p = EXP2F(fmaf(e, L2E, -rl2));       // unnormalized weight <= 1
            p = ((word >> (kg * 8 + j)) & 1u) ? p : 0.f;
            rsum += p;
            af.u[j] = f2bf_fast(p);
        }
        const unsigned short* bp = WhB + (size_t)(kw0 + st) * (NFB * 512) + (size_t)lane * 8;
#pragma unroll
        for (int fb = 0; fb < NFB; fb++) {
            bf16x8_t bfrag = *(const bf16x8_t*)(bp + (size_t)fb * 512);
            acc[fb] = __builtin_amdgcn_mfma_f32_16x16x32_bf16(af.v, bfrag, acc[fb], 0, 0, 0);
        }
    }
    // row-sum partials: lanes {l,l+16,l+32,l+48} hold row R0+l
    rsum += __shfl_xor(rsum, 16);
    rsum += __shfl_xor(rsum, 32);
    if (lane < 16) sred[wave][lane] = rsum;
    // spill acc to LDS (D layout: col=fl, row=kg*4+r)
#pragma unroll
    for (int fb = 0; fb < NFB; fb++)
#pragma unroll
        for (int r = 0; r < 4; r++)
            acc_lds[wave][kg * 4 + r][fb * 16 + fl] = acc[fb][r];
    __syncthreads();

    // cross-wave reduce + normalize + ELU -> h_lds (and hL write if FINAL)
#pragma unroll
    for (int q = 0; q < (16 * F) / 256; q++) {
        int cell = q * 256 + tid;
        int r = cell / F, c = cell % F;
        float s = acc_lds[0][r][c] + acc_lds[1][r][c] + acc_lds[2][r][c] + acc_lds[3][r][c];
        float S = sred[0][r] + sred[1][r] + sred[2][r] + sred[3][r];
        float h = S > 0.f ? s / S : 0.f;
        h = h > 0.f ? h : (__expf(h) - 1.f);
        h_lds[r][c] = h;
        if (FINAL) hL_out[(size_t)(R0 + r) * F + c] = h;
    }
    __syncthreads();

    int r = tid >> 4, cc = (tid & 15) * 2;             // 16 rows x 16 col-pairs (32 cols)
    if (!FINAL) {
        // Wh2 = h1 @ W2 (16x64 @ 64x32), then a2 dots + WhB2 scatter
        float w0 = 0.f, w1 = 0.f;
#pragma unroll
        for (int f = 0; f < 64; f++) {
            float hf = h_lds[r][f];
            w0 += hf * W2[f * 32 + cc];
            w1 += hf * W2[f * 32 + cc + 1];
        }
        float vi = w0 * a2[cc] + w1 * a2[cc + 1];
        float vk = w0 * a2[32 + cc] + w1 * a2[32 + cc + 1];
#pragma unroll
        for (int off = 8; off; off >>= 1) { vi += __shfl_xor(vi, off); vk += __shfl_xor(vk, off); }
        if ((tid & 15) == 0) { si2[R0 + r] = vi; sk2[R0 + r] = vk; }
        int i = R0 + r;
        WhB2[whb_idx(i, cc, 2)]     = f2bf(w0);
        WhB2[whb_idx(i, cc + 1, 2)] = f2bf(w1);
    } else {
        // omega dots over hL
        float h0v = h_lds[r][cc], h1v = h_lds[r][cc + 1];
        float vi = h0v * omega[cc] + h1v * omega[cc + 1];
        float vk = h0v * omega[32 + cc] + h1v * omega[32 + cc + 1];
#pragma unroll
        for (int off = 8; off; off >>= 1) { vi += __shfl_xor(vi, off); vk += __shfl_xor(vk, off); }
        if ((tid & 15) == 0) { p_i[R0 + r] = vi; p_k[R0 + r] = vk; }
    }
}

// ---------------- final pairwise sigmoid (grid-stride x4) ----------------
__global__ __launch_bounds__(256) void pred_kernel(const float* __restrict__ p_i,
                                                   const float* __restrict__ p_k,
                                                   float* __restrict__ out) {
    int gid = blockIdx.x * 256 + threadIdx.x;          // 0 .. M*M/16-1
#pragma unroll
    for (int t = 0; t < 4; t++) {
        int idx4 = gid + t * (M * M / 16);
        int i = idx4 / (M / 4);
        int k4 = (idx4 % (M / 4)) * 4;
        float pi = p_i[i];
        float4 pk = *(const float4*)&p_k[k4];
        float4 o;
        o.x = 1.f / (1.f + __expf(-(pi + pk.x)));
        o.y = 1.f / (1.f + __expf(-(pi + pk.y)));
        o.z = 1.f / (1.f + __expf(-(pi + pk.z)));
        o.w = 1.f / (1.f + __expf(-(pi + pk.w)));
        *(float4*)&out[(size_t)i * M + k4] = o;
    }
}

extern "C" void kernel_launch(void* const* d_in, const int* in_sizes, int n_in,
                              void* d_out, int out_size, void* d_ws, size_t ws_size,
                              hipStream_t stream) {
    const float* h0    = (const float*)d_in[0];
    const int*   adj   = (const int*)d_in[1];
    const float* W1    = (const float*)d_in[2];
    const float* a1    = (const float*)d_in[3];
    const float* W2    = (const float*)d_in[4];
    const float* a2    = (const float*)d_in[5];
    const float* omega = (const float*)d_in[6];
    float* out = (float*)d_out;

    char* ws = (char*)d_ws;
    unsigned int*   packedT = (unsigned int*)(ws + 0);         // 2 MB (transposed bits)
    unsigned short* WhB1    = (unsigned short*)(ws + 2097152); // 512 KB
    unsigned short* WhB2    = (unsigned short*)(ws + 2621440); // 256 KB
    float* si1 = (float*)(ws + 2883584);
    float* sk1 = (float*)(ws + 2899968);
    float* si2 = (float*)(ws + 2916352);
    float* sk2 = (float*)(ws + 2932736);
    float* pi  = (float*)(ws + 2949120);
    float* pk  = (float*)(ws + 2965504);

    // K1: pack (16384 blocks) || layer-1 GEMM/svec (1024 blocks)
    prep_fat_kernel<64, 64><<<PACK_BLOCKS + M / 4, 256, 0, stream>>>(
        adj, packedT, h0, W1, a1, WhB1, si1, sk1);

    // K2: layer-1 attention full-K + fused mid epilogue (-> WhB2, si2, sk2)
    attn_full_kernel<64, false><<<M / 16, 256, 0, stream>>>(
        WhB1, si1, sk1, packedT, W2, a2, WhB2, si2, sk2, nullptr, nullptr, nullptr, nullptr);

    // K3: layer-2 attention full-K + fused out epilogue (-> hL tail, pi, pk)
    attn_full_kernel<32, true><<<M / 16, 256, 0, stream>>>(
        WhB2, si2, sk2, packedT, nullptr, nullptr, nullptr, nullptr, nullptr,
        omega, out + (size_t)M * M, pi, pk);

    // K4: pairwise sigmoid
    pred_kernel<<<M * M / 16 / 256, 256, 0, stream>>>(pi, pk, out);
}